// Round 2
// baseline (1122.256 us; speedup 1.0000x reference)
//
#include <hip/hip_runtime.h>
#include <hip/hip_bf16.h>
#include <stdint.h>

#define M_TOT 8192
#define N_TOT 16384
#define K_TOT 4096

typedef int v4i __attribute__((ext_vector_type(4)));

__device__ __forceinline__ float fix_scale(float s) { return s == 0.0f ? 1.0f : s; }

__device__ __forceinline__ void gload_lds16(const void* g, void* l) {
    __builtin_amdgcn_global_load_lds((__attribute__((address_space(1))) void*)g,
                                     (__attribute__((address_space(3))) void*)l,
                                     16, 0, 0);
}

// swizzle within a [row][64B] LDS tile: permute 16B granules by row bits.
// involution; confined to byte-bits 4..5, keyed by bits 7..8 (row>>1).
__device__ __forceinline__ int swz(int byte_off) {
    return byte_off ^ (((byte_off >> 7) & 3) << 4);
}

__device__ __forceinline__ int8_t quant1(float x, float scale) {
    float r = fminf(127.0f, fmaxf(-127.0f, rintf(x / scale)));
    return (int8_t)(int)r;
}

// ---------------- lhs: per-row absmax quantize ----------------
__global__ __launch_bounds__(256) void k_quant_lhs(const float* __restrict__ x,
                                                   int8_t* __restrict__ q,
                                                   float* __restrict__ s) {
    const int row = blockIdx.x;
    const int t = threadIdx.x;
    const float* xr = x + (size_t)row * K_TOT;
    float4 v[4];
    float m = 0.0f;
#pragma unroll
    for (int i = 0; i < 4; ++i) {
        v[i] = ((const float4*)xr)[i * 256 + t];
        m = fmaxf(m, fmaxf(fmaxf(fabsf(v[i].x), fabsf(v[i].y)),
                           fmaxf(fabsf(v[i].z), fabsf(v[i].w))));
    }
#pragma unroll
    for (int off = 32; off; off >>= 1) m = fmaxf(m, __shfl_xor(m, off));
    __shared__ float wmax[4];
    if ((t & 63) == 0) wmax[t >> 6] = m;
    __syncthreads();
    m = fmaxf(fmaxf(wmax[0], wmax[1]), fmaxf(wmax[2], wmax[3]));
    const float scale = fix_scale(m / 127.0f);
    if (t == 0) s[row] = scale;
    unsigned* qrow = (unsigned*)(q + (size_t)row * K_TOT);
#pragma unroll
    for (int i = 0; i < 4; ++i) {
        unsigned b0 = (unsigned char)quant1(v[i].x, scale);
        unsigned b1 = (unsigned char)quant1(v[i].y, scale);
        unsigned b2 = (unsigned char)quant1(v[i].z, scale);
        unsigned b3 = (unsigned char)quant1(v[i].w, scale);
        qrow[i * 256 + t] = b0 | (b1 << 8) | (b2 << 16) | (b3 << 24);
    }
}

// ---------------- rhs: per-column absmax (atomicMax on float bits) ----------------
__global__ __launch_bounds__(256) void k_rhs_absmax(const float* __restrict__ rhs,
                                                    unsigned* __restrict__ amax) {
    const int f = blockIdx.x * 256 + threadIdx.x;
    const int d0 = blockIdx.y * 256;
    const float* p = rhs + (size_t)d0 * N_TOT + f;
    float m = 0.0f;
#pragma unroll 4
    for (int d = 0; d < 256; ++d)
        m = fmaxf(m, fabsf(p[(size_t)d * N_TOT]));
    atomicMax(amax + f, __float_as_uint(m));
}

__global__ __launch_bounds__(256) void k_rhs_scale(const unsigned* __restrict__ amax,
                                                   float* __restrict__ s) {
    const int f = blockIdx.x * 256 + threadIdx.x;
    s[f] = fix_scale(__uint_as_float(amax[f]) / 127.0f);
}

// ---------------- rhs: quantize + transpose to [N][K] ----------------
__global__ __launch_bounds__(256) void k_quant_rhs_t(const float* __restrict__ rhs,
                                                     const float* __restrict__ s,
                                                     int8_t* __restrict__ qT) {
    const int f0 = blockIdx.x * 64;
    const int d0 = blockIdx.y * 64;
    const int t = threadIdx.x;
    __shared__ float sc[64];
    __shared__ alignas(16) int8_t tile[64][64];  // [f local][d local]
    if (t < 64) sc[t] = s[f0 + t];
    __syncthreads();
    const int fl = (t & 15) * 4;
    const int rl = t >> 4;
#pragma unroll
    for (int i = 0; i < 4; ++i) {
        const int dl = i * 16 + rl;
        float4 v = *(const float4*)(rhs + (size_t)(d0 + dl) * N_TOT + f0 + fl);
        tile[fl + 0][dl] = quant1(v.x, sc[fl + 0]);
        tile[fl + 1][dl] = quant1(v.y, sc[fl + 1]);
        tile[fl + 2][dl] = quant1(v.z, sc[fl + 2]);
        tile[fl + 3][dl] = quant1(v.w, sc[fl + 3]);
    }
    __syncthreads();
    const int fr = t >> 2;
    const int dc = (t & 3) * 16;
    *(int4*)(qT + (size_t)(f0 + fr) * K_TOT + d0 + dc) = *(const int4*)&tile[fr][dc];
}

// ---------------- int8 GEMM: C[m][n] = acc(i32) * sA[m] * sB[n] ----------------
#define BM 128
#define BN 128
#define BK 64
#define NKT (K_TOT / BK)

__global__ __launch_bounds__(256) void k_gemm(const int8_t* __restrict__ qA,   // [M][K]
                                              const int8_t* __restrict__ qB,   // [N][K]
                                              const float* __restrict__ sA,
                                              const float* __restrict__ sB,
                                              float* __restrict__ C) {
    __shared__ alignas(16) int8_t As[2][BM * BK];
    __shared__ alignas(16) int8_t Bs[2][BN * BK];

    // bijective XCD swizzle (nwg = 8192, divisible by 8)
    const int nwg_x = N_TOT / BN;               // 128
    const int bid = blockIdx.y * nwg_x + blockIdx.x;
    const int cpx = (nwg_x * (M_TOT / BM)) / 8; // 1024
    const int swzb = (bid & 7) * cpx + (bid >> 3);
    const int bn0 = (swzb % nwg_x) * BN;
    const int bm0 = (swzb / nwg_x) * BM;

    const int tid = threadIdx.x;
    const int wave = tid >> 6;
    const int lane = tid & 63;
    const int wm = (wave >> 1) * 64;
    const int wn = (wave & 1) * 64;

    const int flat0 = wave * 1024 + lane * 16;  // this lane's linear LDS dest
    // pre-swizzled global source coords (rule #21: linear dest + inv-swz source)
    int srow[2], scol[2];
#pragma unroll
    for (int i = 0; i < 2; ++i) {
        const int logical = swz(i * 4096 + flat0);
        srow[i] = logical >> 6;
        scol[i] = logical & 63;
    }

    v4i acc[4][4];
#pragma unroll
    for (int i = 0; i < 4; ++i)
#pragma unroll
        for (int j = 0; j < 4; ++j) {
            v4i z = {0, 0, 0, 0};
            acc[i][j] = z;
        }

    auto stage = [&](int buf, int kt) {
        const int k0 = kt * BK;
#pragma unroll
        for (int i = 0; i < 2; ++i) {
            gload_lds16(qA + (size_t)(bm0 + srow[i]) * K_TOT + k0 + scol[i],
                        &As[buf][i * 4096 + wave * 1024]);
            gload_lds16(qB + (size_t)(bn0 + srow[i]) * K_TOT + k0 + scol[i],
                        &Bs[buf][i * 4096 + wave * 1024]);
        }
    };

    stage(0, 0);
    __syncthreads();

    const int frow = lane & 15;         // row within 16x16 tile
    const int fcol = (lane >> 4) * 16;  // byte col (k) within BK
    // precomputed swizzled read offsets
    int offA[4], offB[4];
#pragma unroll
    for (int i = 0; i < 4; ++i) {
        offA[i] = swz((wm + i * 16 + frow) * BK + fcol);
        offB[i] = swz((wn + i * 16 + frow) * BK + fcol);
    }

    for (int kt = 0; kt < NKT; ++kt) {
        const int buf = kt & 1;
        if (kt + 1 < NKT) stage(buf ^ 1, kt + 1);
        v4i af[4], bf[4];
#pragma unroll
        for (int i = 0; i < 4; ++i) {
            af[i] = *(const v4i*)&As[buf][offA[i]];
            bf[i] = *(const v4i*)&Bs[buf][offB[i]];
        }
#pragma unroll
        for (int i = 0; i < 4; ++i)
#pragma unroll
            for (int j = 0; j < 4; ++j)
                acc[i][j] = __builtin_amdgcn_mfma_i32_16x16x64_i8(af[i], bf[j], acc[i][j], 0, 0, 0);
        __syncthreads();
    }

    // epilogue: dequant + store
    const int cr = (lane >> 4) * 4;  // row offset within 16x16 C tile
    const int cc = lane & 15;        // col within tile
#pragma unroll
    for (int i = 0; i < 4; ++i) {
        const int gr0 = bm0 + wm + i * 16 + cr;
#pragma unroll
        for (int j = 0; j < 4; ++j) {
            const int gc = bn0 + wn + j * 16 + cc;
            const float sb = sB[gc];
#pragma unroll
            for (int r = 0; r < 4; ++r) {
                const int gr = gr0 + r;
                C[(size_t)gr * N_TOT + gc] = (float)acc[i][j][r] * sA[gr] * sb;
            }
        }
    }
}

extern "C" void kernel_launch(void* const* d_in, const int* in_sizes, int n_in,
                              void* d_out, int out_size, void* d_ws, size_t ws_size,
                              hipStream_t stream) {
    const float* lhs = (const float*)d_in[0];
    const float* rhs = (const float*)d_in[1];
    float* out = (float*)d_out;
    char* ws = (char*)d_ws;

    int8_t* qA = (int8_t*)ws;                                   // 32 MB
    int8_t* qB = (int8_t*)(ws + (size_t)33554432);              // 64 MB
    float* sA = (float*)(ws + (size_t)33554432 + 67108864);     // 32 KB
    float* sB = sA + M_TOT;                                     // 64 KB
    unsigned* amax = (unsigned*)(sB + N_TOT);                   // 64 KB

    hipMemsetAsync(amax, 0, N_TOT * sizeof(unsigned), stream);

    k_quant_lhs<<<M_TOT, 256, 0, stream>>>(lhs, qA, sA);
    k_rhs_absmax<<<dim3(N_TOT / 256, K_TOT / 256), 256, 0, stream>>>(rhs, amax);
    k_rhs_scale<<<N_TOT / 256, 256, 0, stream>>>(amax, sB);
    k_quant_rhs_t<<<dim3(N_TOT / 64, K_TOT / 64), 256, 0, stream>>>(rhs, sB, qB);
    k_gemm<<<dim3(N_TOT / BN, M_TOT / BM), 256, 0, stream>>>(qA, qB, sA, sB, out);
}

// Round 3
// 878.698 us; speedup vs baseline: 1.2772x; 1.2772x over previous
//
#include <hip/hip_runtime.h>
#include <hip/hip_bf16.h>
#include <stdint.h>

#define M_TOT 8192
#define N_TOT 16384
#define K_TOT 4096

typedef int v4i __attribute__((ext_vector_type(4)));

__device__ __forceinline__ float fix_scale(float s) { return s == 0.0f ? 1.0f : s; }

__device__ __forceinline__ void gload_lds16(const void* g, void* l) {
    __builtin_amdgcn_global_load_lds((__attribute__((address_space(1))) void*)g,
                                     (__attribute__((address_space(3))) void*)l,
                                     16, 0, 0);
}

// LDS swizzle for [row][64B] tiles: XOR 16B-granule bits (4..5) with row bits 1..2
// (byte bits 7..8). Involution; verified conflict-free in round 2 (6.7e7 -> 0).
__device__ __forceinline__ int swz(int byte_off) {
    return byte_off ^ (((byte_off >> 7) & 3) << 4);
}

__device__ __forceinline__ int8_t quant1(float x, float scale) {
    float r = fminf(127.0f, fmaxf(-127.0f, rintf(x / scale)));
    return (int8_t)(int)r;
}

// ---------------- lhs: per-row absmax quantize ----------------
__global__ __launch_bounds__(256) void k_quant_lhs(const float* __restrict__ x,
                                                   int8_t* __restrict__ q,
                                                   float* __restrict__ s) {
    const int row = blockIdx.x;
    const int t = threadIdx.x;
    const float* xr = x + (size_t)row * K_TOT;
    float4 v[4];
    float m = 0.0f;
#pragma unroll
    for (int i = 0; i < 4; ++i) {
        v[i] = ((const float4*)xr)[i * 256 + t];
        m = fmaxf(m, fmaxf(fmaxf(fabsf(v[i].x), fabsf(v[i].y)),
                           fmaxf(fabsf(v[i].z), fabsf(v[i].w))));
    }
#pragma unroll
    for (int off = 32; off; off >>= 1) m = fmaxf(m, __shfl_xor(m, off));
    __shared__ float wmax[4];
    if ((t & 63) == 0) wmax[t >> 6] = m;
    __syncthreads();
    m = fmaxf(fmaxf(wmax[0], wmax[1]), fmaxf(wmax[2], wmax[3]));
    const float scale = fix_scale(m / 127.0f);
    if (t == 0) s[row] = scale;
    unsigned* qrow = (unsigned*)(q + (size_t)row * K_TOT);
#pragma unroll
    for (int i = 0; i < 4; ++i) {
        unsigned b0 = (unsigned char)quant1(v[i].x, scale);
        unsigned b1 = (unsigned char)quant1(v[i].y, scale);
        unsigned b2 = (unsigned char)quant1(v[i].z, scale);
        unsigned b3 = (unsigned char)quant1(v[i].w, scale);
        qrow[i * 256 + t] = b0 | (b1 << 8) | (b2 << 16) | (b3 << 24);
    }
}

// ---------------- rhs: per-column absmax (atomicMax on float bits) ----------------
__global__ __launch_bounds__(256) void k_rhs_absmax(const float* __restrict__ rhs,
                                                    unsigned* __restrict__ amax) {
    const int f = blockIdx.x * 256 + threadIdx.x;
    const int d0 = blockIdx.y * 256;
    const float* p = rhs + (size_t)d0 * N_TOT + f;
    float m = 0.0f;
#pragma unroll 4
    for (int d = 0; d < 256; ++d)
        m = fmaxf(m, fabsf(p[(size_t)d * N_TOT]));
    atomicMax(amax + f, __float_as_uint(m));
}

__global__ __launch_bounds__(256) void k_rhs_scale(const unsigned* __restrict__ amax,
                                                   float* __restrict__ s) {
    const int f = blockIdx.x * 256 + threadIdx.x;
    s[f] = fix_scale(__uint_as_float(amax[f]) / 127.0f);
}

// ---------------- rhs: quantize + transpose to [N][K] ----------------
__global__ __launch_bounds__(256) void k_quant_rhs_t(const float* __restrict__ rhs,
                                                     const float* __restrict__ s,
                                                     int8_t* __restrict__ qT) {
    const int f0 = blockIdx.x * 64;
    const int d0 = blockIdx.y * 64;
    const int t = threadIdx.x;
    __shared__ float sc[64];
    __shared__ alignas(16) int8_t tile[64][64];  // [f local][d local]
    if (t < 64) sc[t] = s[f0 + t];
    __syncthreads();
    const int fl = (t & 15) * 4;
    const int rl = t >> 4;
#pragma unroll
    for (int i = 0; i < 4; ++i) {
        const int dl = i * 16 + rl;
        float4 v = *(const float4*)(rhs + (size_t)(d0 + dl) * N_TOT + f0 + fl);
        tile[fl + 0][dl] = quant1(v.x, sc[fl + 0]);
        tile[fl + 1][dl] = quant1(v.y, sc[fl + 1]);
        tile[fl + 2][dl] = quant1(v.z, sc[fl + 2]);
        tile[fl + 3][dl] = quant1(v.w, sc[fl + 3]);
    }
    __syncthreads();
    const int fr = t >> 2;
    const int dc = (t & 3) * 16;
    *(int4*)(qT + (size_t)(f0 + fr) * K_TOT + d0 + dc) = *(const int4*)&tile[fr][dc];
}

// ---------------- int8 GEMM, 256x256 tile, counted-vmcnt 4-deep pipeline ----------------
#define BM 256
#define BN 256
#define BK 64
#define NKT (K_TOT / BK)   // 64

__global__ __launch_bounds__(512, 2) void k_gemm(const int8_t* __restrict__ qA,   // [M][K]
                                                 const int8_t* __restrict__ qB,   // [N][K]
                                                 const float* __restrict__ sA,
                                                 const float* __restrict__ sB,
                                                 float* __restrict__ C) {
    __shared__ alignas(1024) int8_t As[4][BM * BK];   // 4 x 16 KB
    __shared__ alignas(1024) int8_t Bs[4][BM * BK];   // 4 x 16 KB  (128 KB total)

    // supercolumn raster: width 2 bn-tiles; keeps all XCDs in the same region
    // (round 2 lesson: partitioning XCDs across bm-regions thrashed L3).
    const int bid = blockIdx.x;          // 0..2047
    const int sc = bid >> 6;             // 32 supercolumns
    const int ii = bid & 63;
    const int bm0 = (ii & 31) * BM;
    const int bn0 = ((sc << 1) | (ii >> 5)) * BN;

    const int tid = threadIdx.x;
    const int wave = tid >> 6;
    const int lane = tid & 63;
    const int wm = (wave >> 2) * 128;    // 2 wave-rows
    const int wn = (wave & 3) * 64;      // 4 wave-cols

    // staging: linear LDS dest + inverse-swizzled global source (rule #21)
    const int8_t* aSrc[2];
    const int8_t* bSrc[2];
    int dstOff[2];
#pragma unroll
    for (int i = 0; i < 2; ++i) {
        const int p = i * 8192 + tid * 16;
        const int l = swz(p);
        dstOff[i] = p;
        aSrc[i] = qA + (size_t)(bm0 + (l >> 6)) * K_TOT + (l & 63);
        bSrc[i] = qB + (size_t)(bn0 + (l >> 6)) * K_TOT + (l & 63);
    }

    // swizzled fragment read offsets
    int offA[2][4], offB[4];
#pragma unroll
    for (int mh = 0; mh < 2; ++mh)
#pragma unroll
        for (int f = 0; f < 4; ++f)
            offA[mh][f] = swz((wm + mh * 64 + f * 16 + (lane & 15)) * BK + (lane >> 4) * 16);
#pragma unroll
    for (int j = 0; j < 4; ++j)
        offB[j] = swz((wn + j * 16 + (lane & 15)) * BK + (lane >> 4) * 16);

    v4i acc[8][4];
#pragma unroll
    for (int i = 0; i < 8; ++i)
#pragma unroll
        for (int j = 0; j < 4; ++j) {
            v4i z = {0, 0, 0, 0};
            acc[i][j] = z;
        }

    auto stageA = [&](int kt) {
        const int buf = kt & 3;
#pragma unroll
        for (int i = 0; i < 2; ++i)
            gload_lds16(aSrc[i] + kt * BK, &As[buf][dstOff[i]]);
    };
    auto stageB = [&](int kt) {
        const int buf = kt & 3;
#pragma unroll
        for (int i = 0; i < 2; ++i)
            gload_lds16(bSrc[i] + kt * BK, &Bs[buf][dstOff[i]]);
    };

    // prologue: stage kt=0,1,2 (12 loads in flight), wait oldest 4 (kt0)
    stageA(0); stageB(0);
    stageA(1); stageB(1);
    stageA(2); stageB(2);
    asm volatile("s_waitcnt vmcnt(8)" ::: "memory");
    __builtin_amdgcn_s_barrier();

    for (int kt = 0; kt < NKT; ++kt) {
        const int buf = kt & 3;
        const int8_t* a = As[buf];
        const int8_t* b = Bs[buf];

        if (kt + 3 < NKT) stageA(kt + 3);

        v4i bf[4];
#pragma unroll
        for (int j = 0; j < 4; ++j) bf[j] = *(const v4i*)(b + offB[j]);
        v4i af[4];
#pragma unroll
        for (int f = 0; f < 4; ++f) af[f] = *(const v4i*)(a + offA[0][f]);

        __builtin_amdgcn_s_setprio(1);
#pragma unroll
        for (int f = 0; f < 4; ++f)
#pragma unroll
            for (int j = 0; j < 4; ++j)
                acc[f][j] = __builtin_amdgcn_mfma_i32_16x16x64_i8(af[f], bf[j], acc[f][j], 0, 0, 0);
        __builtin_amdgcn_s_setprio(0);

        if (kt + 3 < NKT) stageB(kt + 3);

#pragma unroll
        for (int f = 0; f < 4; ++f) af[f] = *(const v4i*)(a + offA[1][f]);

        __builtin_amdgcn_s_setprio(1);
#pragma unroll
        for (int f = 0; f < 4; ++f)
#pragma unroll
            for (int j = 0; j < 4; ++j)
                acc[4 + f][j] = __builtin_amdgcn_mfma_i32_16x16x64_i8(af[f], bf[j], acc[4 + f][j], 0, 0, 0);
        __builtin_amdgcn_s_setprio(0);

        if (kt < NKT - 1) {
            // counted vmcnt: keep the 2 newer K-tiles' loads (8) in flight;
            // drain only at the pipeline tail.
            if (kt <= NKT - 4)      asm volatile("s_waitcnt vmcnt(8)" ::: "memory");
            else if (kt == NKT - 3) asm volatile("s_waitcnt vmcnt(4)" ::: "memory");
            else                    asm volatile("s_waitcnt vmcnt(0)" ::: "memory");
            __builtin_amdgcn_s_barrier();
        }
    }

    // epilogue: dequant + store
    const int cc = lane & 15;
    const int cr = (lane >> 4) * 4;
#pragma unroll
    for (int mi = 0; mi < 8; ++mi) {
        const int gr0 = bm0 + wm + mi * 16 + cr;
        float sa[4];
#pragma unroll
        for (int r = 0; r < 4; ++r) sa[r] = sA[gr0 + r];
#pragma unroll
        for (int j = 0; j < 4; ++j) {
            const int gc = bn0 + wn + j * 16 + cc;
            const float sb = sB[gc];
#pragma unroll
            for (int r = 0; r < 4; ++r)
                C[(size_t)(gr0 + r) * N_TOT + gc] = (float)acc[mi][j][r] * sa[r] * sb;
        }
    }
}

extern "C" void kernel_launch(void* const* d_in, const int* in_sizes, int n_in,
                              void* d_out, int out_size, void* d_ws, size_t ws_size,
                              hipStream_t stream) {
    const float* lhs = (const float*)d_in[0];
    const float* rhs = (const float*)d_in[1];
    float* out = (float*)d_out;
    char* ws = (char*)d_ws;

    int8_t* qA = (int8_t*)ws;                                   // 32 MB
    int8_t* qB = (int8_t*)(ws + (size_t)33554432);              // 64 MB
    float* sA = (float*)(ws + (size_t)33554432 + 67108864);     // 32 KB
    float* sB = sA + M_TOT;                                     // 64 KB
    unsigned* amax = (unsigned*)(sB + N_TOT);                   // 64 KB

    hipMemsetAsync(amax, 0, N_TOT * sizeof(unsigned), stream);

    k_quant_lhs<<<M_TOT, 256, 0, stream>>>(lhs, qA, sA);
    k_rhs_absmax<<<dim3(N_TOT / 256, K_TOT / 256), 256, 0, stream>>>(rhs, amax);
    k_rhs_scale<<<N_TOT / 256, 256, 0, stream>>>(amax, sB);
    k_quant_rhs_t<<<dim3(N_TOT / 64, K_TOT / 64), 256, 0, stream>>>(rhs, sB, qB);
    k_gemm<<<(M_TOT / BM) * (N_TOT / BN), 512, 0, stream>>>(qA, qB, sA, sB, out);
}

// Round 4
// 841.589 us; speedup vs baseline: 1.3335x; 1.0441x over previous
//
#include <hip/hip_runtime.h>
#include <hip/hip_bf16.h>
#include <stdint.h>

#define M_TOT 8192
#define N_TOT 16384
#define K_TOT 4096

typedef int v4i __attribute__((ext_vector_type(4)));

__device__ __forceinline__ float fix_scale(float s) { return s == 0.0f ? 1.0f : s; }

__device__ __forceinline__ void gload_lds16(const void* g, void* l) {
    __builtin_amdgcn_global_load_lds((__attribute__((address_space(1))) void*)g,
                                     (__attribute__((address_space(3))) void*)l,
                                     16, 0, 0);
}

// LDS swizzle for [row][64B] tiles: XOR 16B-granule bits (4..5) with row bits 1..2
// (byte bits 7..8). Involution; verified conflict-free in round 2 (6.7e7 -> 0).
__device__ __forceinline__ int swz(int byte_off) {
    return byte_off ^ (((byte_off >> 7) & 3) << 4);
}

__device__ __forceinline__ int8_t quant1(float x, float scale) {
    float r = fminf(127.0f, fmaxf(-127.0f, rintf(x / scale)));
    return (int8_t)(int)r;
}

// ---------------- lhs: per-row absmax quantize ----------------
__global__ __launch_bounds__(256) void k_quant_lhs(const float* __restrict__ x,
                                                   int8_t* __restrict__ q,
                                                   float* __restrict__ s) {
    const int row = blockIdx.x;
    const int t = threadIdx.x;
    const float* xr = x + (size_t)row * K_TOT;
    float4 v[4];
    float m = 0.0f;
#pragma unroll
    for (int i = 0; i < 4; ++i) {
        v[i] = ((const float4*)xr)[i * 256 + t];
        m = fmaxf(m, fmaxf(fmaxf(fabsf(v[i].x), fabsf(v[i].y)),
                           fmaxf(fabsf(v[i].z), fabsf(v[i].w))));
    }
#pragma unroll
    for (int off = 32; off; off >>= 1) m = fmaxf(m, __shfl_xor(m, off));
    __shared__ float wmax[4];
    if ((t & 63) == 0) wmax[t >> 6] = m;
    __syncthreads();
    m = fmaxf(fmaxf(wmax[0], wmax[1]), fmaxf(wmax[2], wmax[3]));
    const float scale = fix_scale(m / 127.0f);
    if (t == 0) s[row] = scale;
    unsigned* qrow = (unsigned*)(q + (size_t)row * K_TOT);
#pragma unroll
    for (int i = 0; i < 4; ++i) {
        unsigned b0 = (unsigned char)quant1(v[i].x, scale);
        unsigned b1 = (unsigned char)quant1(v[i].y, scale);
        unsigned b2 = (unsigned char)quant1(v[i].z, scale);
        unsigned b3 = (unsigned char)quant1(v[i].w, scale);
        qrow[i * 256 + t] = b0 | (b1 << 8) | (b2 << 16) | (b3 << 24);
    }
}

// ---------------- rhs: per-column absmax (atomicMax on float bits) ----------------
__global__ __launch_bounds__(256) void k_rhs_absmax(const float* __restrict__ rhs,
                                                    unsigned* __restrict__ amax) {
    const int f = blockIdx.x * 256 + threadIdx.x;
    const int d0 = blockIdx.y * 256;
    const float* p = rhs + (size_t)d0 * N_TOT + f;
    float m = 0.0f;
#pragma unroll 4
    for (int d = 0; d < 256; ++d)
        m = fmaxf(m, fabsf(p[(size_t)d * N_TOT]));
    atomicMax(amax + f, __float_as_uint(m));
}

__global__ __launch_bounds__(256) void k_rhs_scale(const unsigned* __restrict__ amax,
                                                   float* __restrict__ s) {
    const int f = blockIdx.x * 256 + threadIdx.x;
    s[f] = fix_scale(__uint_as_float(amax[f]) / 127.0f);
}

// ---------------- rhs: quantize + transpose to [N][K] ----------------
__global__ __launch_bounds__(256) void k_quant_rhs_t(const float* __restrict__ rhs,
                                                     const float* __restrict__ s,
                                                     int8_t* __restrict__ qT) {
    const int f0 = blockIdx.x * 64;
    const int d0 = blockIdx.y * 64;
    const int t = threadIdx.x;
    __shared__ float sc[64];
    __shared__ alignas(16) int8_t tile[64][64];  // [f local][d local]
    if (t < 64) sc[t] = s[f0 + t];
    __syncthreads();
    const int fl = (t & 15) * 4;
    const int rl = t >> 4;
#pragma unroll
    for (int i = 0; i < 4; ++i) {
        const int dl = i * 16 + rl;
        float4 v = *(const float4*)(rhs + (size_t)(d0 + dl) * N_TOT + f0 + fl);
        tile[fl + 0][dl] = quant1(v.x, sc[fl + 0]);
        tile[fl + 1][dl] = quant1(v.y, sc[fl + 1]);
        tile[fl + 2][dl] = quant1(v.z, sc[fl + 2]);
        tile[fl + 3][dl] = quant1(v.w, sc[fl + 3]);
    }
    __syncthreads();
    const int fr = t >> 2;
    const int dc = (t & 3) * 16;
    *(int4*)(qT + (size_t)(f0 + fr) * K_TOT + d0 + dc) = *(const int4*)&tile[fr][dc];
}

// ---------------- int8 GEMM, 256x256 tile, m201-style phase schedule ----------------
#define BM 256
#define BN 256
#define BK 64
#define NKT (K_TOT / BK)   // 64

__global__ __launch_bounds__(512, 2) void k_gemm(const int8_t* __restrict__ qA,   // [M][K]
                                                 const int8_t* __restrict__ qB,   // [N][K]
                                                 const float* __restrict__ sA,
                                                 const float* __restrict__ sB,
                                                 float* __restrict__ C) {
    __shared__ alignas(1024) int8_t As[4][BM * BK];   // 4 x 16 KB
    __shared__ alignas(1024) int8_t Bs[4][BM * BK];   // 4 x 16 KB  (128 KB total)

    // supercolumn raster: width 2 bn-tiles (round-3 verified: FETCH 2.14GB -> 394MB)
    const int bid = blockIdx.x;          // 0..2047
    const int sc = bid >> 6;             // 32 supercolumns
    const int ii = bid & 63;
    const int bm0 = (ii & 31) * BM;
    const int bn0 = ((sc << 1) | (ii >> 5)) * BN;

    const int tid = threadIdx.x;
    const int wave = tid >> 6;
    const int lane = tid & 63;
    const int wm = (wave >> 2) * 128;    // 2 wave-rows
    const int wn = (wave & 3) * 64;      // 4 wave-cols

    // staging: linear LDS dest + inverse-swizzled global source (rule #21)
    const int8_t* aSrc[2];
    const int8_t* bSrc[2];
    int dstOff[2];
#pragma unroll
    for (int i = 0; i < 2; ++i) {
        const int p = i * 8192 + tid * 16;
        const int l = swz(p);
        dstOff[i] = p;
        aSrc[i] = qA + (size_t)(bm0 + (l >> 6)) * K_TOT + (l & 63);
        bSrc[i] = qB + (size_t)(bn0 + (l >> 6)) * K_TOT + (l & 63);
    }

    // swizzled fragment read offsets
    int offA[2][4], offB[4];
#pragma unroll
    for (int mh = 0; mh < 2; ++mh)
#pragma unroll
        for (int f = 0; f < 4; ++f)
            offA[mh][f] = swz((wm + mh * 64 + f * 16 + (lane & 15)) * BK + (lane >> 4) * 16);
#pragma unroll
    for (int j = 0; j < 4; ++j)
        offB[j] = swz((wn + j * 16 + (lane & 15)) * BK + (lane >> 4) * 16);

    v4i acc[8][4];
#pragma unroll
    for (int i = 0; i < 8; ++i)
#pragma unroll
        for (int j = 0; j < 4; ++j) {
            v4i z = {0, 0, 0, 0};
            acc[i][j] = z;
        }

    auto stageA = [&](int kt) {
        const int buf = kt & 3;
#pragma unroll
        for (int i = 0; i < 2; ++i)
            gload_lds16(aSrc[i] + kt * BK, &As[buf][dstOff[i]]);
    };
    auto stageB = [&](int kt) {
        const int buf = kt & 3;
#pragma unroll
        for (int i = 0; i < 2; ++i)
            gload_lds16(bSrc[i] + kt * BK, &Bs[buf][dstOff[i]]);
    };

    // prologue: stage kt=0,1,2 (12 loads in flight), wait for kt0's 4
    stageA(0); stageB(0);
    stageA(1); stageB(1);
    stageA(2); stageB(2);
    asm volatile("s_waitcnt vmcnt(8)" ::: "memory");
    __builtin_amdgcn_s_barrier();

    for (int kt = 0; kt < NKT; ++kt) {
        const int buf = kt & 3;
        const int8_t* a = As[buf];
        const int8_t* b = Bs[buf];

        // ================= phase 0: B frags + A m-half 0, stage A(kt+3) ========
        v4i bf[4], af[4];
#pragma unroll
        for (int j = 0; j < 4; ++j) bf[j] = *(const v4i*)(b + offB[j]);
#pragma unroll
        for (int f = 0; f < 4; ++f) af[f] = *(const v4i*)(a + offA[0][f]);
        if (kt + 3 < NKT) stageA(kt + 3);

        __builtin_amdgcn_s_barrier();
        asm volatile("s_waitcnt lgkmcnt(0)" ::: "memory");
        __builtin_amdgcn_s_setprio(1);
#pragma unroll
        for (int f = 0; f < 4; ++f)
#pragma unroll
            for (int j = 0; j < 4; ++j)
                acc[f][j] = __builtin_amdgcn_mfma_i32_16x16x64_i8(af[f], bf[j], acc[f][j], 0, 0, 0);
        __builtin_amdgcn_s_setprio(0);
        __builtin_amdgcn_s_barrier();

        // ================= phase 1: A m-half 1, stage B(kt+3) ==================
        v4i af2[4];
#pragma unroll
        for (int f = 0; f < 4; ++f) af2[f] = *(const v4i*)(a + offA[1][f]);
        if (kt + 3 < NKT) stageB(kt + 3);

        __builtin_amdgcn_s_barrier();
        asm volatile("s_waitcnt lgkmcnt(0)" ::: "memory");
        __builtin_amdgcn_s_setprio(1);
#pragma unroll
        for (int f = 0; f < 4; ++f)
#pragma unroll
            for (int j = 0; j < 4; ++j)
                acc[4 + f][j] = __builtin_amdgcn_mfma_i32_16x16x64_i8(af2[f], bf[j], acc[4 + f][j], 0, 0, 0);
        __builtin_amdgcn_s_setprio(0);

        if (kt < NKT - 1) {
            // counted vmcnt once per K-tile (never 0 in steady state):
            // keep kt+2/kt+3's 8 loads in flight, drain only kt+1's.
            if (kt <= NKT - 4)      asm volatile("s_waitcnt vmcnt(8)" ::: "memory");
            else if (kt == NKT - 3) asm volatile("s_waitcnt vmcnt(4)" ::: "memory");
            else                    asm volatile("s_waitcnt vmcnt(0)" ::: "memory");
            __builtin_amdgcn_s_barrier();
        }
    }

    // epilogue: dequant + store
    const int cc = lane & 15;
    const int cr = (lane >> 4) * 4;
#pragma unroll
    for (int mi = 0; mi < 8; ++mi) {
        const int gr0 = bm0 + wm + mi * 16 + cr;
        float sa[4];
#pragma unroll
        for (int r = 0; r < 4; ++r) sa[r] = sA[gr0 + r];
#pragma unroll
        for (int j = 0; j < 4; ++j) {
            const int gc = bn0 + wn + j * 16 + cc;
            const float sb = sB[gc];
#pragma unroll
            for (int r = 0; r < 4; ++r)
                C[(size_t)(gr0 + r) * N_TOT + gc] = (float)acc[mi][j][r] * sa[r] * sb;
        }
    }
}

extern "C" void kernel_launch(void* const* d_in, const int* in_sizes, int n_in,
                              void* d_out, int out_size, void* d_ws, size_t ws_size,
                              hipStream_t stream) {
    const float* lhs = (const float*)d_in[0];
    const float* rhs = (const float*)d_in[1];
    float* out = (float*)d_out;
    char* ws = (char*)d_ws;

    int8_t* qA = (int8_t*)ws;                                   // 32 MB
    int8_t* qB = (int8_t*)(ws + (size_t)33554432);              // 64 MB
    float* sA = (float*)(ws + (size_t)33554432 + 67108864);     // 32 KB
    float* sB = sA + M_TOT;                                     // 64 KB
    unsigned* amax = (unsigned*)(sB + N_TOT);                   // 64 KB

    hipMemsetAsync(amax, 0, N_TOT * sizeof(unsigned), stream);

    k_quant_lhs<<<M_TOT, 256, 0, stream>>>(lhs, qA, sA);
    k_rhs_absmax<<<dim3(N_TOT / 256, K_TOT / 256), 256, 0, stream>>>(rhs, amax);
    k_rhs_scale<<<N_TOT / 256, 256, 0, stream>>>(amax, sB);
    k_quant_rhs_t<<<dim3(N_TOT / 64, K_TOT / 64), 256, 0, stream>>>(rhs, sB, qB);
    k_gemm<<<(M_TOT / BM) * (N_TOT / BN), 512, 0, stream>>>(qA, qB, sA, sB, out);
}

// Round 5
// 818.358 us; speedup vs baseline: 1.3714x; 1.0284x over previous
//
#include <hip/hip_runtime.h>
#include <hip/hip_bf16.h>
#include <stdint.h>

#define M_TOT 8192
#define N_TOT 16384
#define K_TOT 4096

typedef int v4i __attribute__((ext_vector_type(4)));

__device__ __forceinline__ float fix_scale(float s) { return s == 0.0f ? 1.0f : s; }

__device__ __forceinline__ void gload_lds16(const void* g, void* l) {
    __builtin_amdgcn_global_load_lds((__attribute__((address_space(1))) void*)g,
                                     (__attribute__((address_space(3))) void*)l,
                                     16, 0, 0);
}

// LDS swizzle for [row][64B] tiles: XOR 16B-granule bits (4..5) with row bits 1..2
// (byte bits 7..8). Involution; verified conflict-free (round 2: 6.7e7 -> 0).
__device__ __forceinline__ int swz(int byte_off) {
    return byte_off ^ (((byte_off >> 7) & 3) << 4);
}

__device__ __forceinline__ int8_t quant1(float x, float scale) {
    float r = fminf(127.0f, fmaxf(-127.0f, rintf(x / scale)));
    return (int8_t)(int)r;
}

// ---------------- lhs: per-row absmax quantize ----------------
__global__ __launch_bounds__(256) void k_quant_lhs(const float* __restrict__ x,
                                                   int8_t* __restrict__ q,
                                                   float* __restrict__ s) {
    const int row = blockIdx.x;
    const int t = threadIdx.x;
    const float* xr = x + (size_t)row * K_TOT;
    float4 v[4];
    float m = 0.0f;
#pragma unroll
    for (int i = 0; i < 4; ++i) {
        v[i] = ((const float4*)xr)[i * 256 + t];
        m = fmaxf(m, fmaxf(fmaxf(fabsf(v[i].x), fabsf(v[i].y)),
                           fmaxf(fabsf(v[i].z), fabsf(v[i].w))));
    }
#pragma unroll
    for (int off = 32; off; off >>= 1) m = fmaxf(m, __shfl_xor(m, off));
    __shared__ float wmax[4];
    if ((t & 63) == 0) wmax[t >> 6] = m;
    __syncthreads();
    m = fmaxf(fmaxf(wmax[0], wmax[1]), fmaxf(wmax[2], wmax[3]));
    const float scale = fix_scale(m / 127.0f);
    if (t == 0) s[row] = scale;
    unsigned* qrow = (unsigned*)(q + (size_t)row * K_TOT);
#pragma unroll
    for (int i = 0; i < 4; ++i) {
        unsigned b0 = (unsigned char)quant1(v[i].x, scale);
        unsigned b1 = (unsigned char)quant1(v[i].y, scale);
        unsigned b2 = (unsigned char)quant1(v[i].z, scale);
        unsigned b3 = (unsigned char)quant1(v[i].w, scale);
        qrow[i * 256 + t] = b0 | (b1 << 8) | (b2 << 16) | (b3 << 24);
    }
}

// ---------------- rhs: per-column absmax (atomicMax on float bits) ----------------
__global__ __launch_bounds__(256) void k_rhs_absmax(const float* __restrict__ rhs,
                                                    unsigned* __restrict__ amax) {
    const int f = blockIdx.x * 256 + threadIdx.x;
    const int d0 = blockIdx.y * 256;
    const float* p = rhs + (size_t)d0 * N_TOT + f;
    float m = 0.0f;
#pragma unroll 4
    for (int d = 0; d < 256; ++d)
        m = fmaxf(m, fabsf(p[(size_t)d * N_TOT]));
    atomicMax(amax + f, __float_as_uint(m));
}

__global__ __launch_bounds__(256) void k_rhs_scale(const unsigned* __restrict__ amax,
                                                   float* __restrict__ s) {
    const int f = blockIdx.x * 256 + threadIdx.x;
    s[f] = fix_scale(__uint_as_float(amax[f]) / 127.0f);
}

// ---------------- rhs: quantize + transpose to [N][K] ----------------
__global__ __launch_bounds__(256) void k_quant_rhs_t(const float* __restrict__ rhs,
                                                     const float* __restrict__ s,
                                                     int8_t* __restrict__ qT) {
    const int f0 = blockIdx.x * 64;
    const int d0 = blockIdx.y * 64;
    const int t = threadIdx.x;
    __shared__ float sc[64];
    __shared__ alignas(16) int8_t tile[64][64];  // [f local][d local]
    if (t < 64) sc[t] = s[f0 + t];
    __syncthreads();
    const int fl = (t & 15) * 4;
    const int rl = t >> 4;
#pragma unroll
    for (int i = 0; i < 4; ++i) {
        const int dl = i * 16 + rl;
        float4 v = *(const float4*)(rhs + (size_t)(d0 + dl) * N_TOT + f0 + fl);
        tile[fl + 0][dl] = quant1(v.x, sc[fl + 0]);
        tile[fl + 1][dl] = quant1(v.y, sc[fl + 1]);
        tile[fl + 2][dl] = quant1(v.z, sc[fl + 2]);
        tile[fl + 3][dl] = quant1(v.w, sc[fl + 3]);
    }
    __syncthreads();
    const int fr = t >> 2;
    const int dc = (t & 3) * 16;
    *(int4*)(qT + (size_t)(f0 + fr) * K_TOT + d0 + dc) = *(const int4*)&tile[fr][dc];
}

// ---------------- int8 GEMM: 256x128 tile, 8 waves of 64x64, 2 blocks/CU ----------------
#define BM 256
#define BN 128
#define BK 64
#define NKT (K_TOT / BK)   // 64

__global__ __launch_bounds__(512, 4) void k_gemm(const int8_t* __restrict__ qA,   // [M][K]
                                                 const int8_t* __restrict__ qB,   // [N][K]
                                                 const float* __restrict__ sA,
                                                 const float* __restrict__ sB,
                                                 float* __restrict__ C) {
    __shared__ alignas(1024) int8_t As[3][BM * BK];   // 3 x 16 KB
    __shared__ alignas(1024) int8_t Bs[3][BN * BK];   // 3 x  8 KB  (72 KB total)

    // supercolumn raster: 4 bn-tiles (512 cols) wide, column-major inside.
    // grid = 32 m-tiles x 128 n-tiles = 4096 blocks.
    const int bid = blockIdx.x;
    const int sc = bid >> 7;             // 32 supercolumns
    const int ii = bid & 127;
    const int bm0 = (ii & 31) << 8;                    // (ii&31)*256
    const int bn0 = (((sc << 2) | (ii >> 5))) << 7;    // n-tile * 128

    const int tid = threadIdx.x;
    const int wave = tid >> 6;
    const int lane = tid & 63;
    const int wm = (wave >> 1) * 64;     // 4 wave-rows
    const int wn = (wave & 1) * 64;      // 2 wave-cols

    // staging: linear LDS dest + inverse-swizzled global source (rule #21)
    const int8_t* aSrc[2];
    const int8_t* bSrc;
    {
#pragma unroll
        for (int i = 0; i < 2; ++i) {
            const int l = swz(i * 8192 + tid * 16);
            aSrc[i] = qA + (size_t)(bm0 + (l >> 6)) * K_TOT + (l & 63);
        }
        const int l = swz(tid * 16);
        bSrc = qB + (size_t)(bn0 + (l >> 6)) * K_TOT + (l & 63);
    }

    // swizzled fragment read offsets
    int offA[4], offB[4];
#pragma unroll
    for (int f = 0; f < 4; ++f) {
        offA[f] = swz((wm + f * 16 + (lane & 15)) * BK + (lane >> 4) * 16);
        offB[f] = swz((wn + f * 16 + (lane & 15)) * BK + (lane >> 4) * 16);
    }

    v4i acc[4][4];
#pragma unroll
    for (int i = 0; i < 4; ++i)
#pragma unroll
        for (int j = 0; j < 4; ++j) {
            v4i z = {0, 0, 0, 0};
            acc[i][j] = z;
        }

    auto stage = [&](int kt, int b) {
#pragma unroll
        for (int i = 0; i < 2; ++i)
            gload_lds16(aSrc[i] + kt * BK, &As[b][i * 8192 + tid * 16]);
        gload_lds16(bSrc + kt * BK, &Bs[b][tid * 16]);
    };

    // prologue: stage kt=0 (buf0), kt=1 (buf1): 6 loads out; wait kt0's 3.
    stage(0, 0);
    stage(1, 1);
    asm volatile("s_waitcnt vmcnt(3)" ::: "memory");
    __builtin_amdgcn_s_barrier();

    int bufc = 0;
    for (int kt = 0; kt < NKT; ++kt) {
        const int bnext = (bufc == 2) ? 0 : bufc + 1;
        const int bstage = (bnext == 2) ? 0 : bnext + 1;
        if (kt + 2 < NKT) stage(kt + 2, bstage);

        const int8_t* a = As[bufc];
        const int8_t* b = Bs[bufc];
        v4i af[4], bf[4];
#pragma unroll
        for (int f = 0; f < 4; ++f) {
            af[f] = *(const v4i*)(a + offA[f]);
            bf[f] = *(const v4i*)(b + offB[f]);
        }

        __builtin_amdgcn_s_setprio(1);
#pragma unroll
        for (int f = 0; f < 4; ++f)
#pragma unroll
            for (int j = 0; j < 4; ++j)
                acc[f][j] = __builtin_amdgcn_mfma_i32_16x16x64_i8(af[f], bf[j], acc[f][j], 0, 0, 0);
        __builtin_amdgcn_s_setprio(0);

        if (kt + 1 < NKT) {
            // counted vmcnt: keep kt+2's 3 loads in flight; drain only kt+1's.
            if (kt + 2 < NKT) asm volatile("s_waitcnt vmcnt(3)" ::: "memory");
            else              asm volatile("s_waitcnt vmcnt(0)" ::: "memory");
            __builtin_amdgcn_s_barrier();
        }
        bufc = bnext;
    }

    // epilogue: dequant + store
    const int cc = lane & 15;
    const int cr = (lane >> 4) * 4;
#pragma unroll
    for (int mi = 0; mi < 4; ++mi) {
        const int gr0 = bm0 + wm + mi * 16 + cr;
        float sa[4];
#pragma unroll
        for (int r = 0; r < 4; ++r) sa[r] = sA[gr0 + r];
#pragma unroll
        for (int j = 0; j < 4; ++j) {
            const int gc = bn0 + wn + j * 16 + cc;
            const float sb = sB[gc];
#pragma unroll
            for (int r = 0; r < 4; ++r)
                C[(size_t)(gr0 + r) * N_TOT + gc] = (float)acc[mi][j][r] * sa[r] * sb;
        }
    }
}

extern "C" void kernel_launch(void* const* d_in, const int* in_sizes, int n_in,
                              void* d_out, int out_size, void* d_ws, size_t ws_size,
                              hipStream_t stream) {
    const float* lhs = (const float*)d_in[0];
    const float* rhs = (const float*)d_in[1];
    float* out = (float*)d_out;
    char* ws = (char*)d_ws;

    int8_t* qA = (int8_t*)ws;                                   // 32 MB
    int8_t* qB = (int8_t*)(ws + (size_t)33554432);              // 64 MB
    float* sA = (float*)(ws + (size_t)33554432 + 67108864);     // 32 KB
    float* sB = sA + M_TOT;                                     // 64 KB
    unsigned* amax = (unsigned*)(sB + N_TOT);                   // 64 KB

    hipMemsetAsync(amax, 0, N_TOT * sizeof(unsigned), stream);

    k_quant_lhs<<<M_TOT, 256, 0, stream>>>(lhs, qA, sA);
    k_rhs_absmax<<<dim3(N_TOT / 256, K_TOT / 256), 256, 0, stream>>>(rhs, amax);
    k_rhs_scale<<<N_TOT / 256, 256, 0, stream>>>(amax, sB);
    k_quant_rhs_t<<<dim3(N_TOT / 64, K_TOT / 64), 256, 0, stream>>>(rhs, sB, qB);
    k_gemm<<<(M_TOT / BM) * (N_TOT / BN), 512, 0, stream>>>(qA, qB, sA, sB, out);
}